// Round 1
// 411.071 us; speedup vs baseline: 1.0172x; 1.0172x over previous
//
#include <hip/hip_runtime.h>

// DisplacementVectorsASU: out[i] = frac[e0[i]] - ( wrap(symm[i][0:3] @ [frac[e1[i]],1]) + ct[i] )
// wrap(x) = x - floor(x).
//
// R5: all streaming operands (symm tile, eidx, ct) are loaded with
// __builtin_nontemporal_load (TCC evict-first). Theory: the 384 MB stream
// turns each XCD's 4 MiB L2 over ~12x per run and evicts the 1.6 MB fracp
// gather table, so a large fraction of the 8M random 16B gathers miss to HBM
// (64 B/line -> up to ~512 MB of extra fetch). NT-marking the streams keeps
// the table L2-resident; gathers themselves stay default-cached.
// R4 (kept): symm staged via fully-contiguous dwordx4 into a skewed LDS tile;
// gathers are single dwordx4 into the float4-padded node table in d_ws.

typedef float vf4 __attribute__((ext_vector_type(4)));

__global__ __launch_bounds__(256) void pad_frac_kernel(
    const float* __restrict__ frac, vf4* __restrict__ fracp, int N)
{
    int i = blockIdx.x * blockDim.x + threadIdx.x;
    if (i < N) {
        vf4 v;
        v.x = frac[3 * i + 0];
        v.y = frac[3 * i + 1];
        v.z = frac[3 * i + 2];
        v.w = 0.0f;
        fracp[i] = v;
    }
}

// Full 256-edge tiles only (tail handled by scalar kernel).
__global__ __launch_bounds__(256) void disp_vec_main(
    const vf4*   __restrict__ fracp,   // (N) padded nodes, L2-resident
    const int*   __restrict__ eidx,    // (2,M)
    const float* __restrict__ symm,    // (M,4,4)
    const float* __restrict__ ct,      // (M,3)
    float*       __restrict__ out,     // (M,3)
    int M)
{
    // symm tile: 256 edges * 4 rows = 1024 vf4, skewed (+1 slot per 8) = 1152
    __shared__ vf4   sy[1152];          // 18432 B
    __shared__ float so[768];           // out staging, 3072 B

    const int tid  = threadIdx.x;
    const int base = blockIdx.x * 256;
    const int i    = base + tid;

    // ---- stage symm tile: 4 fully-contiguous NT vf4 loads per thread ----
    const vf4* sg = (const vf4*)(symm + (size_t)base * 16);
    #pragma unroll
    for (int k = 0; k < 4; ++k) {
        const int slot = k * 256 + tid;
        sy[slot + (slot >> 3)] = __builtin_nontemporal_load(sg + slot);
    }

    // ---- per-edge streamed operands (coalesced, NT) ----
    const int n0 = __builtin_nontemporal_load(eidx + i);
    const int n1 = __builtin_nontemporal_load(eidx + M + i);
    const float c0 = __builtin_nontemporal_load(ct + 3 * (size_t)i + 0);
    const float c1 = __builtin_nontemporal_load(ct + 3 * (size_t)i + 1);
    const float c2 = __builtin_nontemporal_load(ct + 3 * (size_t)i + 2);

    // ---- gathers: single dwordx4 each, default caching (want L2 residency) ----
    const vf4 fin = fracp[n0];
    const vf4 fo  = fracp[n1];

    __syncthreads();                    // symm tile visible

    const int s0 = 4 * tid;
    const vf4 r0 = sy[s0     + ((s0    ) >> 3)];
    const vf4 r1 = sy[s0 + 1 + ((s0 + 1) >> 3)];
    const vf4 r2 = sy[s0 + 2 + ((s0 + 2) >> 3)];

    float t0 = fo.x * r0.x + fo.y * r0.y + fo.z * r0.z + r0.w;
    float t1 = fo.x * r1.x + fo.y * r1.y + fo.z * r1.z + r1.w;
    float t2 = fo.x * r2.x + fo.y * r2.y + fo.z * r2.z + r2.w;

    t0 -= floorf(t0);
    t1 -= floorf(t1);
    t2 -= floorf(t2);

    so[3 * tid + 0] = fin.x - (t0 + c0);
    so[3 * tid + 1] = fin.y - (t1 + c1);
    so[3 * tid + 2] = fin.z - (t2 + c2);
    __syncthreads();

    // ---- write out tile: 192 coalesced vf4 nt-stores ----
    if (tid < 192) {
        vf4* o4 = (vf4*)(out + (size_t)base * 3);
        __builtin_nontemporal_store(((vf4*)so)[tid], o4 + tid);
    }
    (void)M;
}

// Scalar tail / fallback — same math.
__global__ __launch_bounds__(256) void disp_vec_scalar(
    const float* __restrict__ frac,
    const int*   __restrict__ eidx,
    const float* __restrict__ symm,
    const float* __restrict__ ct,
    float*       __restrict__ out,
    int M, int start)
{
    int i = start + blockIdx.x * blockDim.x + threadIdx.x;
    if (i >= M) return;

    int n0 = eidx[i];
    int n1 = eidx[M + i];

    const float* f0 = frac + (size_t)n0 * 3;
    const float* f1 = frac + (size_t)n1 * 3;

    const float4* s = (const float4*)(symm + (size_t)i * 16);
    float4 r0 = s[0], r1 = s[1], r2 = s[2];

    float ox = f1[0], oy = f1[1], oz = f1[2];
    float t0 = ox * r0.x + oy * r0.y + oz * r0.z + r0.w;
    float t1 = ox * r1.x + oy * r1.y + oz * r1.z + r1.w;
    float t2 = ox * r2.x + oy * r2.y + oz * r2.z + r2.w;

    t0 -= floorf(t0);
    t1 -= floorf(t1);
    t2 -= floorf(t2);

    const float* c = ct + (size_t)i * 3;
    float* o = out + (size_t)i * 3;
    o[0] = f0[0] - (t0 + c[0]);
    o[1] = f0[1] - (t1 + c[1]);
    o[2] = f0[2] - (t2 + c[2]);
}

extern "C" void kernel_launch(void* const* d_in, const int* in_sizes, int n_in,
                              void* d_out, int out_size, void* d_ws, size_t ws_size,
                              hipStream_t stream) {
    const float* frac = (const float*)d_in[0];   // (N,3) f32
    const int*   eidx = (const int*)d_in[1];     // (2,M) i32
    const float* symm = (const float*)d_in[2];   // (M,4,4) f32
    const float* ct   = (const float*)d_in[3];   // (M,3) f32
    float* out = (float*)d_out;                  // (M,3) f32

    const int N = in_sizes[0] / 3;               // 100,000 nodes
    const int M = in_sizes[1] / 2;               // 4,000,000 edges

    const size_t need = (size_t)N * sizeof(vf4);
    if (ws_size >= need) {
        vf4* fracp = (vf4*)d_ws;
        pad_frac_kernel<<<(N + 255) / 256, 256, 0, stream>>>(frac, fracp, N);

        const int full_tiles = M / 256;
        const int rem        = M % 256;          // 0 for M = 4,000,000
        if (full_tiles > 0) {
            disp_vec_main<<<full_tiles, 256, 0, stream>>>(fracp, eidx, symm, ct, out, M);
        }
        if (rem > 0) {
            disp_vec_scalar<<<1, 256, 0, stream>>>(frac, eidx, symm, ct, out, M, full_tiles * 256);
        }
    } else {
        disp_vec_scalar<<<(M + 255) / 256, 256, 0, stream>>>(frac, eidx, symm, ct, out, M, 0);
    }
}

// Round 3
// 410.362 us; speedup vs baseline: 1.0190x; 1.0017x over previous
//
#include <hip/hip_runtime.h>

// DisplacementVectorsASU: out[i] = frac[e0[i]] - ( wrap(symm[i][0:3] @ [frac[e1[i]],1]) + ct[i] )
// wrap(x) = x - floor(x).
//
// R6 (resubmit after infra flake): rows-0..2-only symm LDS tile (row 3 never
// used; the 64B line is fetched by HBM anyway, but LDS drops 18KiB->12KiB =>
// 8 blocks/CU = 32/32 waves, was 28/32). The 48B/edge layout makes
// ds_read_b128 row reads conflict-free with NO skew (word addr 12t+4r covers
// all 8 bank quads per 8 lanes). ct is staged through the (otherwise idle)
// out-staging buffer as coalesced NT vf4 loads and read back at stride-3
// (2 lanes/bank = free). eidx + gathers hoisted to the top so the dependent
// chain starts before staging.
// R5 (kept): NT loads on all streams. R4 (kept): gathers are single dwordx4
// into the float4-padded node table in d_ws.

typedef float vf4 __attribute__((ext_vector_type(4)));

__global__ __launch_bounds__(256) void pad_frac_kernel(
    const float* __restrict__ frac, vf4* __restrict__ fracp, int N)
{
    int i = blockIdx.x * blockDim.x + threadIdx.x;
    if (i < N) {
        vf4 v;
        v.x = frac[3 * i + 0];
        v.y = frac[3 * i + 1];
        v.z = frac[3 * i + 2];
        v.w = 0.0f;
        fracp[i] = v;
    }
}

// Full 256-edge tiles only (tail handled by scalar kernel).
__global__ __launch_bounds__(256) void disp_vec_main(
    const vf4*   __restrict__ fracp,   // (N) padded nodes, L2-resident
    const int*   __restrict__ eidx,    // (2,M)
    const float* __restrict__ symm,    // (M,4,4)
    const float* __restrict__ ct,      // (M,3)
    float*       __restrict__ out,     // (M,3)
    int M)
{
    __shared__ vf4 sy[768];            // symm rows 0..2 of 256 edges, 12288 B
    __shared__ vf4 so4[192];           // ct staging, then out staging, 3072 B
    float* sof = (float*)so4;

    const int tid  = threadIdx.x;
    const int base = blockIdx.x * 256;
    const int i    = base + tid;

    // ---- eidx + gathers first: start the dependent chain ASAP ----
    const int n0 = __builtin_nontemporal_load(eidx + i);
    const int n1 = __builtin_nontemporal_load(eidx + M + i);
    const vf4 fin = fracp[n0];
    const vf4 fo  = fracp[n1];

    // ---- stage symm rows 0..2: 3 NT vf4 loads per thread ----
    // LDS slot s = 3*edge + row  <-  global vf4 index 4*edge + row
    const vf4* sg = (const vf4*)(symm + (size_t)base * 16);
    #pragma unroll
    for (int k = 0; k < 3; ++k) {
        const int s = k * 256 + tid;   // 0..767
        const int e = s / 3;
        const int r = s - 3 * e;
        sy[s] = __builtin_nontemporal_load(sg + 4 * e + r);
    }

    // ---- stage ct tile: 192 coalesced NT vf4 loads ----
    if (tid < 192) {
        const vf4* cg = (const vf4*)(ct + (size_t)base * 3);
        so4[tid] = __builtin_nontemporal_load(cg + tid);
    }

    __syncthreads();                    // sy + ct tile visible

    // ---- conflict-free row reads (stride 48 B) ----
    const vf4 r0 = sy[3 * tid + 0];
    const vf4 r1 = sy[3 * tid + 1];
    const vf4 r2 = sy[3 * tid + 2];

    const float c0 = sof[3 * tid + 0];
    const float c1 = sof[3 * tid + 1];
    const float c2 = sof[3 * tid + 2];

    float t0 = fo.x * r0.x + fo.y * r0.y + fo.z * r0.z + r0.w;
    float t1 = fo.x * r1.x + fo.y * r1.y + fo.z * r1.z + r1.w;
    float t2 = fo.x * r2.x + fo.y * r2.y + fo.z * r2.z + r2.w;

    t0 -= floorf(t0);
    t1 -= floorf(t1);
    t2 -= floorf(t2);

    const float o0 = fin.x - (t0 + c0);
    const float o1 = fin.y - (t1 + c1);
    const float o2 = fin.z - (t2 + c2);

    __syncthreads();                    // done reading ct from so4

    sof[3 * tid + 0] = o0;              // stride-3: 2 lanes/bank, free
    sof[3 * tid + 1] = o1;
    sof[3 * tid + 2] = o2;
    __syncthreads();

    // ---- write out tile: 192 coalesced vf4 nt-stores ----
    if (tid < 192) {
        vf4* o4 = (vf4*)(out + (size_t)base * 3);
        __builtin_nontemporal_store(so4[tid], o4 + tid);
    }
    (void)M;
}

// Scalar tail / fallback — same math.
__global__ __launch_bounds__(256) void disp_vec_scalar(
    const float* __restrict__ frac,
    const int*   __restrict__ eidx,
    const float* __restrict__ symm,
    const float* __restrict__ ct,
    float*       __restrict__ out,
    int M, int start)
{
    int i = start + blockIdx.x * blockDim.x + threadIdx.x;
    if (i >= M) return;

    int n0 = eidx[i];
    int n1 = eidx[M + i];

    const float* f0 = frac + (size_t)n0 * 3;
    const float* f1 = frac + (size_t)n1 * 3;

    const float4* s = (const float4*)(symm + (size_t)i * 16);
    float4 r0 = s[0], r1 = s[1], r2 = s[2];

    float ox = f1[0], oy = f1[1], oz = f1[2];
    float t0 = ox * r0.x + oy * r0.y + oz * r0.z + r0.w;
    float t1 = ox * r1.x + oy * r1.y + oz * r1.z + r1.w;
    float t2 = ox * r2.x + oy * r2.y + oz * r2.z + r2.w;

    t0 -= floorf(t0);
    t1 -= floorf(t1);
    t2 -= floorf(t2);

    const float* c = ct + (size_t)i * 3;
    float* o = out + (size_t)i * 3;
    o[0] = f0[0] - (t0 + c[0]);
    o[1] = f0[1] - (t1 + c[1]);
    o[2] = f0[2] - (t2 + c[2]);
}

extern "C" void kernel_launch(void* const* d_in, const int* in_sizes, int n_in,
                              void* d_out, int out_size, void* d_ws, size_t ws_size,
                              hipStream_t stream) {
    const float* frac = (const float*)d_in[0];   // (N,3) f32
    const int*   eidx = (const int*)d_in[1];     // (2,M) i32
    const float* symm = (const float*)d_in[2];   // (M,4,4) f32
    const float* ct   = (const float*)d_in[3];   // (M,3) f32
    float* out = (float*)d_out;                  // (M,3) f32

    const int N = in_sizes[0] / 3;               // 100,000 nodes
    const int M = in_sizes[1] / 2;               // 4,000,000 edges

    const size_t need = (size_t)N * sizeof(vf4);
    if (ws_size >= need) {
        vf4* fracp = (vf4*)d_ws;
        pad_frac_kernel<<<(N + 255) / 256, 256, 0, stream>>>(frac, fracp, N);

        const int full_tiles = M / 256;
        const int rem        = M % 256;          // 0 for M = 4,000,000
        if (full_tiles > 0) {
            disp_vec_main<<<full_tiles, 256, 0, stream>>>(fracp, eidx, symm, ct, out, M);
        }
        if (rem > 0) {
            disp_vec_scalar<<<1, 256, 0, stream>>>(frac, eidx, symm, ct, out, M, full_tiles * 256);
        }
    } else {
        disp_vec_scalar<<<(M + 255) / 256, 256, 0, stream>>>(frac, eidx, symm, ct, out, M, 0);
    }
}